// Round 16
// baseline (498.580 us; speedup 1.0000x reference)
//
#include <hip/hip_runtime.h>
#include <hip/hip_bf16.h>
#include <math.h>

// CircumpunctSSM: B=4, T=512, D=1024, S=16, dt_rank=64. All f32.
// Pipeline (R16 = R15 + 256-block fused grid isolation + BK=64 g1a/g5):
//   g1a: siluxz[:, 0:1024]  = silu(x @ W_in[0:1024].T)     [64x64 BK=64, 512 blocks]
//   g24: xpc[2048,160]      = x_in @ [W_xproj;W_res].T     [32x32 BK=32, 320 blocks]
//   g3:  dt[2048,1024]      = softplus(xpc[:,:64]@W_dt.T+b_dt) [K=64 one-shot]
//   FUSED scan+g1b (256 blocks = ~1/CU -> scan CUs private):
//     blocks 0..63   : scan (R10 structure, s_setprio(1), s_barrier)
//     blocks 64..255 : g1b = silu(x @ W_in[1024:2048].T), grid-strided 512 tiles
//   reduce_y: ybuf = (sum_s ypart[s]) * siluz
//   g5: out = ybuf @ W_out.T + b_out            [64x64 BK=64, 512 blocks, plain]
//
// Rules: standalone GEMMs need >=2 blocks/CU (R5/R9/R10); in-shadow g1b at
// 1/CU is fine (covered by scan). Scan: 4 waves x 4 elem optimum (R5/R7/R11).
// s_barrier beats software gates (R14). R14's regression was the spin-gate,
// not the 256-block layout — this round isolates the layout with s_barrier.

enum { EPI_NONE=0, EPI_SILU=1, EPI_SPBIAS=2, EPI_BIAS=3 };

template<int EPI>
__device__ __forceinline__ float epi_apply(float v, float b) {
  if constexpr (EPI == EPI_SILU)        { return v / (1.0f + expf(-v)); }
  else if constexpr (EPI == EPI_SPBIAS) { float t = v + b; return fmaxf(t, 0.0f) + log1pf(expf(-fabsf(t))); }
  else if constexpr (EPI == EPI_BIAS)   { return v + b; }
  else return v;
}

// ---------------- 64x64 tile GEMM, BK=64 + register prefetch (g1a, g5) ----------------
// LDS 2x[64][68] = 34.8 KB -> 2 blocks/CU at 69.6 KB. Staging: lm=tid&63 (row),
// lk=(tid>>6)*16 (wave-uniform k-chunk, 4 float4) — 2-way bank-aliased (free).
template<int EPI>
__global__ __launch_bounds__(256) void gemm_wt(
    const float* __restrict__ A, int lda,
    const float* __restrict__ W, int ldw,
    const float* __restrict__ bias,
    float* __restrict__ C, int ldc,
    int N, int K)
{
  constexpr int BM = 64, BN = 64, BK = 64, PAD = 4;
  __shared__ float As[BK][BM + PAD];
  __shared__ float Ws[BK][BN + PAD];
  const int m0 = blockIdx.x * BM;
  const int n0 = blockIdx.y * BN;
  const int tid = threadIdx.x;
  const int tx = tid & 15;
  const int ty = tid >> 4;
  const int lm = tid & 63;           // staging row
  const int lk = (tid >> 6) << 4;    // 0,16,32,48 (wave-uniform)

  float4 a0, a1, a2, a3, w0, w1, w2, w3;
  {
    const float* p = A + (size_t)(m0 + lm) * lda + lk;
    a0 = ((const float4*)p)[0]; a1 = ((const float4*)p)[1];
    a2 = ((const float4*)p)[2]; a3 = ((const float4*)p)[3];
    const float* pw = W + (size_t)(n0 + lm) * ldw + lk;
    w0 = ((const float4*)pw)[0]; w1 = ((const float4*)pw)[1];
    w2 = ((const float4*)pw)[2]; w3 = ((const float4*)pw)[3];
  }

  float acc[4][4] = {{0.f,0.f,0.f,0.f},{0.f,0.f,0.f,0.f},{0.f,0.f,0.f,0.f},{0.f,0.f,0.f,0.f}};
  const int NT = K / BK;

  for (int i = 0; i < NT; ++i) {
    __syncthreads();   // protect previous iteration's LDS reads
    As[lk+ 0][lm]=a0.x; As[lk+ 1][lm]=a0.y; As[lk+ 2][lm]=a0.z; As[lk+ 3][lm]=a0.w;
    As[lk+ 4][lm]=a1.x; As[lk+ 5][lm]=a1.y; As[lk+ 6][lm]=a1.z; As[lk+ 7][lm]=a1.w;
    As[lk+ 8][lm]=a2.x; As[lk+ 9][lm]=a2.y; As[lk+10][lm]=a2.z; As[lk+11][lm]=a2.w;
    As[lk+12][lm]=a3.x; As[lk+13][lm]=a3.y; As[lk+14][lm]=a3.z; As[lk+15][lm]=a3.w;
    Ws[lk+ 0][lm]=w0.x; Ws[lk+ 1][lm]=w0.y; Ws[lk+ 2][lm]=w0.z; Ws[lk+ 3][lm]=w0.w;
    Ws[lk+ 4][lm]=w1.x; Ws[lk+ 5][lm]=w1.y; Ws[lk+ 6][lm]=w1.z; Ws[lk+ 7][lm]=w1.w;
    Ws[lk+ 8][lm]=w2.x; Ws[lk+ 9][lm]=w2.y; Ws[lk+10][lm]=w2.z; Ws[lk+11][lm]=w2.w;
    Ws[lk+12][lm]=w3.x; Ws[lk+13][lm]=w3.y; Ws[lk+14][lm]=w3.z; Ws[lk+15][lm]=w3.w;
    __syncthreads();
    if (i + 1 < NT) {
      const int k0 = (i + 1) * BK;
      const float* p = A + (size_t)(m0 + lm) * lda + k0 + lk;
      a0 = ((const float4*)p)[0]; a1 = ((const float4*)p)[1];
      a2 = ((const float4*)p)[2]; a3 = ((const float4*)p)[3];
      const float* pw = W + (size_t)(n0 + lm) * ldw + k0 + lk;
      w0 = ((const float4*)pw)[0]; w1 = ((const float4*)pw)[1];
      w2 = ((const float4*)pw)[2]; w3 = ((const float4*)pw)[3];
    }
#pragma unroll
    for (int kk = 0; kk < BK; ++kk) {
      const float4 a = *(const float4*)&As[kk][ty << 2];
      const float4 w = *(const float4*)&Ws[kk][tx << 2];
      const float ar[4] = {a.x, a.y, a.z, a.w};
      const float wr[4] = {w.x, w.y, w.z, w.w};
#pragma unroll
      for (int ii = 0; ii < 4; ++ii)
#pragma unroll
        for (int j = 0; j < 4; ++j)
          acc[ii][j] = fmaf(ar[ii], wr[j], acc[ii][j]);
    }
  }

  const int ncol = n0 + (tx << 2);
  float bj[4] = {0.f, 0.f, 0.f, 0.f};
  if constexpr (EPI == EPI_SPBIAS || EPI == EPI_BIAS) {
    const float4 bv = *(const float4*)(bias + ncol);
    bj[0]=bv.x; bj[1]=bv.y; bj[2]=bv.z; bj[3]=bv.w;
  }
#pragma unroll
  for (int i = 0; i < 4; ++i) {
    float vs[4];
#pragma unroll
    for (int j = 0; j < 4; ++j) vs[j] = epi_apply<EPI>(acc[i][j], bj[j]);
    *(float4*)(C + (size_t)(m0 + (ty << 2) + i) * ldc + ncol) = make_float4(vs[0], vs[1], vs[2], vs[3]);
  }
}

// ---------------- 32x32 dual-W GEMM (fused g2+g4), BK=32 + prefetch ----------------
__global__ __launch_bounds__(256) void gemm_dualw32(
    const float* __restrict__ A, int lda,
    const float* __restrict__ W1,
    const float* __restrict__ W2, int ldw,
    float* __restrict__ C, int ldc, int K)
{
  constexpr int BM = 32, BN = 32, BK = 32, PAD = 4;
  __shared__ float As[BK][BM + PAD];
  __shared__ float Ws[BK][BN + PAD];
  const int m0 = blockIdx.x * BM;
  const int n0 = blockIdx.y * BN;
  const int tid = threadIdx.x;
  const int tx = tid & 15;          // n-pos (2 cols each)
  const int ty = tid >> 4;          // m-pos (2 rows each)
  const int lm = tid & 31;          // staging row
  const int lk = (tid >> 5) << 2;   // 0,4,...,28

  const int n = n0 + lm;
  const float* wrow = (n < 128) ? (W1 + (size_t)n * ldw) : (W2 + (size_t)(n - 128) * ldw);

  float4 av = *(const float4*)(A + (size_t)(m0 + lm) * lda + lk);
  float4 wv = *(const float4*)(wrow + lk);

  float acc[2][2] = {{0.f,0.f},{0.f,0.f}};
  const int NT = K / BK;
  for (int i = 0; i < NT; ++i) {
    __syncthreads();
    As[lk+0][lm]=av.x; As[lk+1][lm]=av.y; As[lk+2][lm]=av.z; As[lk+3][lm]=av.w;
    Ws[lk+0][lm]=wv.x; Ws[lk+1][lm]=wv.y; Ws[lk+2][lm]=wv.z; Ws[lk+3][lm]=wv.w;
    __syncthreads();
    if (i + 1 < NT) {
      const int k0 = (i + 1) * BK;
      av = *(const float4*)(A + (size_t)(m0 + lm) * lda + k0 + lk);
      wv = *(const float4*)(wrow + k0 + lk);
    }
#pragma unroll
    for (int kk = 0; kk < BK; ++kk) {
      const float2 a = *(const float2*)&As[kk][ty << 1];
      const float2 w = *(const float2*)&Ws[kk][tx << 1];
      acc[0][0] = fmaf(a.x, w.x, acc[0][0]);
      acc[0][1] = fmaf(a.x, w.y, acc[0][1]);
      acc[1][0] = fmaf(a.y, w.x, acc[1][0]);
      acc[1][1] = fmaf(a.y, w.y, acc[1][1]);
    }
  }
  const int ncol = n0 + (tx << 1);
  float* pc = C + (size_t)(m0 + (ty << 1)) * ldc + ncol;
  *(float2*)pc         = make_float2(acc[0][0], acc[0][1]);
  *(float2*)(pc + ldc) = make_float2(acc[1][0], acc[1][1]);
}

// ---------------- g3: dt = softplus(xpc[:,:64] @ W_dt.T + b_dt), K=64 one-shot ----
__global__ __launch_bounds__(256) void gemm_dt64(
    const float* __restrict__ A, int lda,
    const float* __restrict__ W,
    const float* __restrict__ bias,
    float* __restrict__ C, int ldc)
{
  __shared__ float As[64][68];
  __shared__ float Ws[64][68];
  const int m0 = blockIdx.x * 64;
  const int n0 = blockIdx.y * 64;
  const int tid = threadIdx.x;
  const int lm = tid & 63;
  const int kq = (tid >> 6) << 4;

  {
    const float* pa = A + (size_t)(m0 + lm) * lda + kq;
    const float4 a0 = ((const float4*)pa)[0];
    const float4 a1 = ((const float4*)pa)[1];
    const float4 a2 = ((const float4*)pa)[2];
    const float4 a3 = ((const float4*)pa)[3];
    const float* pw = W + (size_t)(n0 + lm) * 64 + kq;
    const float4 w0 = ((const float4*)pw)[0];
    const float4 w1 = ((const float4*)pw)[1];
    const float4 w2 = ((const float4*)pw)[2];
    const float4 w3 = ((const float4*)pw)[3];
    As[kq+ 0][lm]=a0.x; As[kq+ 1][lm]=a0.y; As[kq+ 2][lm]=a0.z; As[kq+ 3][lm]=a0.w;
    As[kq+ 4][lm]=a1.x; As[kq+ 5][lm]=a1.y; As[kq+ 6][lm]=a1.z; As[kq+ 7][lm]=a1.w;
    As[kq+ 8][lm]=a2.x; As[kq+ 9][lm]=a2.y; As[kq+10][lm]=a2.z; As[kq+11][lm]=a2.w;
    As[kq+12][lm]=a3.x; As[kq+13][lm]=a3.y; As[kq+14][lm]=a3.z; As[kq+15][lm]=a3.w;
    Ws[kq+ 0][lm]=w0.x; Ws[kq+ 1][lm]=w0.y; Ws[kq+ 2][lm]=w0.z; Ws[kq+ 3][lm]=w0.w;
    Ws[kq+ 4][lm]=w1.x; Ws[kq+ 5][lm]=w1.y; Ws[kq+ 6][lm]=w1.z; Ws[kq+ 7][lm]=w1.w;
    Ws[kq+ 8][lm]=w2.x; Ws[kq+ 9][lm]=w2.y; Ws[kq+10][lm]=w2.z; Ws[kq+11][lm]=w2.w;
    Ws[kq+12][lm]=w3.x; Ws[kq+13][lm]=w3.y; Ws[kq+14][lm]=w3.z; Ws[kq+15][lm]=w3.w;
  }
  __syncthreads();

  const int tx = tid & 15;
  const int ty = tid >> 4;
  float acc[4][4] = {{0.f,0.f,0.f,0.f},{0.f,0.f,0.f,0.f},{0.f,0.f,0.f,0.f},{0.f,0.f,0.f,0.f}};
#pragma unroll 16
  for (int kk = 0; kk < 64; ++kk) {
    const float4 a = *(const float4*)&As[kk][ty << 2];
    const float4 w = *(const float4*)&Ws[kk][tx << 2];
    const float ar[4] = {a.x, a.y, a.z, a.w};
    const float wr[4] = {w.x, w.y, w.z, w.w};
#pragma unroll
    for (int i = 0; i < 4; ++i)
#pragma unroll
      for (int j = 0; j < 4; ++j)
        acc[i][j] = fmaf(ar[i], wr[j], acc[i][j]);
  }

  const int ncol = n0 + (tx << 2);
  const float4 bv = *(const float4*)(bias + ncol);
  const float bj[4] = {bv.x, bv.y, bv.z, bv.w};
#pragma unroll
  for (int i = 0; i < 4; ++i) {
    float vs[4];
#pragma unroll
    for (int j = 0; j < 4; ++j) vs[j] = epi_apply<EPI_SPBIAS>(acc[i][j], bj[j]);
    *(float4*)(C + (size_t)(m0 + (ty << 2) + i) * ldc + ncol) = make_float4(vs[0], vs[1], vs[2], vs[3]);
  }
}

__global__ void zero_kernel(float4* __restrict__ p, int n4) {
  const int i = blockIdx.x * blockDim.x + threadIdx.x;
  if (i < n4) p[i] = make_float4(0.f, 0.f, 0.f, 0.f);
}

// ybuf[i] = (sum_s ypart[s][i]) * siluz[i]
__global__ __launch_bounds__(256) void reduce_y_silu(
    const float4* __restrict__ yp, const float* __restrict__ siluxz,
    float4* __restrict__ yo, int n4)
{
  const int i = blockIdx.x * blockDim.x + threadIdx.x;
  if (i >= n4) return;
  float4 a = yp[i];
#pragma unroll
  for (int s = 1; s < 16; ++s) {
    const float4 v = yp[(size_t)s * 524288 + i];
    a.x += v.x; a.y += v.y; a.z += v.z; a.w += v.w;
  }
  const int row = i >> 8;          // 256 float4 per row of [2048][1024]
  const int c4  = i & 255;
  const float4 z = *(const float4*)(siluxz + (size_t)row * 2048 + 1024 + (c4 << 2));
  a.x *= z.x; a.y *= z.y; a.z *= z.z; a.w *= z.w;
  yo[i] = a;
}

// legacy (atomic fallback path)
__global__ __launch_bounds__(256) void mul_silu(
    float* __restrict__ y, const float* __restrict__ siluxz, int n)
{
  const int i = blockIdx.x * blockDim.x + threadIdx.x;
  if (i >= n) return;
  const int row = i >> 10;
  const int col = i & 1023;
  y[i] *= siluxz[(size_t)row * 2048 + 1024 + col];
}

// --- DPP wave64 sum: 6 dependent full-rate VALU adds. Lane 63 = full sum.
template<int CTRL>
__device__ __forceinline__ float dpp_fadd(float x) {
  const int s = __builtin_amdgcn_update_dpp(0, __float_as_int(x), CTRL, 0xF, 0xF, true);
  return x + __int_as_float(s);
}
__device__ __forceinline__ float wave64_sum_l63(float x) {
  x = dpp_fadd<0x111>(x);   // row_shr:1
  x = dpp_fadd<0x112>(x);   // row_shr:2
  x = dpp_fadd<0x114>(x);   // row_shr:4
  x = dpp_fadd<0x118>(x);   // row_shr:8
  x = dpp_fadd<0x142>(x);   // row_bcast:15
  x = dpp_fadd<0x143>(x);   // row_bcast:31
  return x;
}

// comp for one row; outputs alpha. R9 fold: cm*rr*invr = rr * m2^(-1/6);
// alpha via exp2 with hoisted na2 = -a_s*log2e.
__device__ __forceinline__ void comp_block(const float4& dtv, const float na2,
    const float (&h_r)[4], const float (&h_i)[4], float (&al_out)[4],
    float& wr, float& wi)
{
  const float ta[4] = {dtv.x, dtv.y, dtv.z, dtv.w};
  float sr = 0.f, si = 0.f;
#pragma unroll
  for (int e = 0; e < 4; ++e) {
    const float a = exp2f(ta[e] * na2);
    al_out[e] = a;
    const float om    = 1.0f - a;
    const float rel_r = h_r[e] * om, rel_i = h_i[e] * om;
    const float m2 = fmaf(rel_r, rel_r, fmaf(rel_i, rel_i, 1e-8f));
    const float u  = exp2f(log2f(m2) * (-1.0f / 6.0f));   // mag^(2/3)/mag
    const float rr = rel_r + 1e-10f;
    float cr = rr * u;    cr = fminf(fmaxf(cr, -10.f), 10.f);
    float ci = rel_i * u; ci = fminf(fmaxf(ci, -10.f), 10.f);
    sr += cr; si += ci;
  }
  wr = wave64_sum_l63(sr);
  wi = wave64_sum_l63(si);
}

// One time-step. R9 fold: sfac = Tg * md2^(-1/4).
template<bool PARTIAL>
__device__ __forceinline__ void step_update(
    float& d_r, float& d_i, const float avg_r, const float avg_i,
    const float2& cx, const float4& xv, const float4& dtv,
    const float2& Bv, const float2& Cv,
    const float (&alv)[4], float (&h_r)[4], float (&h_i)[4],
    float* py)
{
  d_r = fmaf(0.01f, avg_r, d_r);
  d_i = fmaf(0.01f, avg_i, d_i);
  const float dm2c = fmaf(d_r, d_r, fmaf(d_i, d_i, 1e-8f));
  if (dm2c > 400.f) { const float sc = 20.f * __builtin_amdgcn_rsqf(dm2c); d_r *= sc; d_i *= sc; }

  const float xr2 = cx.x + 1e-10f;
  const float irx = __builtin_amdgcn_rsqf(fmaf(xr2, xr2, fmaf(cx.y, cx.y, 1e-38f)));
  const float dr2 = d_r + 1e-10f;
  const float ird = __builtin_amdgcn_rsqf(fmaf(dr2, dr2, fmaf(d_i, d_i, 1e-38f)));
  const float cosdp = fmaf(xr2, dr2, cx.y * d_i) * irx * ird;
  const float Tg  = 0.5f * (1.0f + cosdp);
  const float md2 = fmaf(d_r, d_r, fmaf(d_i, d_i, 1e-8f));
  const float sf  = Tg * exp2f(log2f(md2) * -0.25f);
  const float s_r = d_r * sf, s_i = d_i * sf;

  const float xa[4] = {xv.x, xv.y, xv.z, xv.w};
  const float ta[4] = {dtv.x, dtv.y, dtv.z, dtv.w};
  float yv[4];
#pragma unroll
  for (int e = 0; e < 4; ++e) {
    const float bx_r = fmaf(Bv.x, xa[e], s_r) * ta[e];
    const float bx_i = fmaf(Bv.y, xa[e], s_i) * ta[e];
    h_r[e] = fmaf(h_r[e], alv[e], bx_r);
    h_i[e] = fmaf(h_i[e], alv[e], bx_i);
    yv[e] = fmaf(Cv.x, h_r[e], -(Cv.y * h_i[e]));
  }
  if (PARTIAL) {
    *(float4*)py = make_float4(yv[0], yv[1], yv[2], yv[3]);
  } else {
#pragma unroll
    for (int e = 0; e < 4; ++e) atomicAdd(py + e, yv[e]);
  }
}

// One barrier PERIOD = two time-steps (rows RO, RO+1) + comp for row RO+2.
// xpc-derived streams (B/C/xc) have row stride 160.
template<int RB, int RO, bool PARTIAL>
__device__ __forceinline__ void period_body(
    const float* __restrict__ px, const float* __restrict__ pdt,
    const float* __restrict__ pB, const float* __restrict__ pC,
    const float* __restrict__ pxc, float* __restrict__ py,
    const float na2, const int lane, const int wid,
    float (*red)[4][4],
    float& d_r, float& d_i,
    float (&h_r)[4], float (&h_i)[4], float (&al)[4],
    float4& x0, float4& t0, float2& B0, float2& C0, float2& c0,
    float4& x1, float4& t1, float2& B1, float2& C1, float2& c1,
    const float4& t2)
{
  // phase 1: read previous period's partials
  const float4 qa = *(const float4*)&red[RB][0][0];
  const float4 qb = *(const float4*)&red[RB][1][0];
  const float4 qc = *(const float4*)&red[RB][2][0];
  const float4 qd = *(const float4*)&red[RB][3][0];

  // even step (row RO)
  step_update<PARTIAL>(d_r, d_i,
      (qa.x + qb.x + qc.x + qd.x) * (1.0f / 1024.0f),
      (qa.y + qb.y + qc.y + qd.y) * (1.0f / 1024.0f),
      c0, x0, t0, B0, C0, al, h_r, h_i, py + (size_t)RO * 1024);

  // refill slot0 <- row RO+3 (in flight across the barrier; tail reads land
  // in-workspace and are unused)
  x0 = *(const float4*)(px  + (size_t)(RO + 3) * 2048);
  t0 = *(const float4*)(pdt + (size_t)(RO + 3) * 1024);
  B0 = *(const float2*)(pB  + (RO + 3) * 160);
  C0 = *(const float2*)(pC  + (RO + 3) * 160);
  c0 = *(const float2*)(pxc + (RO + 3) * 160);

  // comp for odd row (RO+1) from h(RO)
  float al1[4], w1r, w1i;
  comp_block(t1, na2, h_r, h_i, al1, w1r, w1i);

  // odd step (row RO+1)
  step_update<PARTIAL>(d_r, d_i,
      (qa.z + qb.z + qc.z + qd.z) * (1.0f / 1024.0f),
      (qa.w + qb.w + qc.w + qd.w) * (1.0f / 1024.0f),
      c1, x1, t1, B1, C1, al1, h_r, h_i, py + (size_t)(RO + 1) * 1024);

  // refill slot1 <- row RO+4
  x1 = *(const float4*)(px  + (size_t)(RO + 4) * 2048);
  t1 = *(const float4*)(pdt + (size_t)(RO + 4) * 1024);
  B1 = *(const float2*)(pB  + (RO + 4) * 160);
  C1 = *(const float2*)(pC  + (RO + 4) * 160);
  c1 = *(const float2*)(pxc + (RO + 4) * 160);

  // comp for next even row (RO+2) from h(RO+1); alpha carried out in al
  float w2r, w2i;
  comp_block(t2, na2, h_r, h_i, al, w2r, w2i);

  // one ds_write_b128 carries BOTH partials
  if (lane == 63) *(float4*)&red[(RB + 1) % 3][wid][0] = make_float4(w1r, w1i, w2r, w2i);

  // raw barrier — LDS-only drain; global loads/stores stay in flight
  asm volatile("s_waitcnt lgkmcnt(0)" ::: "memory");
  __builtin_amdgcn_s_barrier();
  asm volatile("" ::: "memory");
}

// FUSED kernel, 256 blocks: blocks 0..63 = scan (private CU each at 1 block/CU);
// blocks 64..255 = g1b 64x64 BK=32 tiles, grid-strided over 512 tiles.
template<bool PARTIAL>
__global__ __launch_bounds__(256) void scan_g1b(
    const float* __restrict__ xin,   // siluxz base, ld 2048 (cols 0..1023 = x_in)
    const float* __restrict__ xpc,   // ld 160
    const float* __restrict__ dtb,   // ld 1024
    const float* __restrict__ A_log, // [16]
    float* __restrict__ ybase,       // PARTIAL ? ypart : ybuf (pre-zeroed)
    int T,
    const float* __restrict__ xg,    // x input, ld 1024 (g1b A operand)
    const float* __restrict__ Wz,    // W_in + 1024*1024 (z-half rows)
    float* __restrict__ Cz)          // siluxz + 1024, ld 2048
{
  if (blockIdx.x < 64) {
    // ---------------- scan branch (R10/R15 structure, verbatim) ----------------
    __builtin_amdgcn_s_setprio(1);

    const int b = blockIdx.x >> 4;
    const int s = blockIdx.x & 15;
    const int d0 = threadIdx.x << 2;
    const int lane = threadIdx.x & 63;
    const int wid = threadIdx.x >> 6;   // 0..3

    __shared__ __align__(16) float red[3][4][4];

    const float a_s = expf(A_log[s]);
    const float na2 = -a_s * 1.4426950408889634f;
    const float phase = (float)(6.283185307179586 * (double)s / 16.0);
    float d_r = 0.01f * cosf(phase);
    float d_i = 0.01f * sinf(phase);
    float h_r[4] = {0.f,0.f,0.f,0.f};
    float h_i[4] = {0.f,0.f,0.f,0.f};
    float al[4];

    const size_t rb = (size_t)b * T;
    const float* px  = xin + rb * 2048 + d0;
    const float* pdt = dtb + rb * 1024 + d0;
    const float* pB  = xpc + rb * 160 + 64 + 2 * s;
    const float* pC  = xpc + rb * 160 + 96 + 2 * s;
    const float* pxc = xpc + rb * 160 + 128 + 2 * s;
    float* py = PARTIAL ? (ybase + (size_t)s * (4 * 512 * 1024) + rb * 1024 + d0)
                        : (ybase + rb * 1024 + d0);

    float4 xA = *(const float4*)px;
    float4 tA = *(const float4*)pdt;
    float2 BA = *(const float2*)pB;
    float2 CA = *(const float2*)pC;
    float2 cA = *(const float2*)pxc;
    float4 xB = *(const float4*)(px + 2048);
    float4 tB = *(const float4*)(pdt + 1024);
    float2 BB = *(const float2*)(pB + 160);
    float2 CB = *(const float2*)(pC + 160);
    float2 cB = *(const float2*)(pxc + 160);
    float4 xC = *(const float4*)(px + 2 * 2048);
    float4 tC = *(const float4*)(pdt + 2 * 1024);
    float2 BC = *(const float2*)(pB + 2 * 160);
    float2 CC = *(const float2*)(pC + 2 * 160);
    float2 cC = *(const float2*)(pxc + 2 * 160);

    {
      float w0r, w0i;
      comp_block(tA, na2, h_r, h_i, al, w0r, w0i);
      if (lane == 63) *(float4*)&red[0][wid][0] = make_float4(0.f, 0.f, w0r, w0i);
    }
    __syncthreads();

    for (int it = 0; it < 85; ++it) {
      period_body<0, 0, PARTIAL>(px, pdt, pB, pC, pxc, py, na2, lane, wid, red,
          d_r, d_i, h_r, h_i, al,
          xA, tA, BA, CA, cA,  xB, tB, BB, CB, cB,  tC);
      period_body<1, 2, PARTIAL>(px, pdt, pB, pC, pxc, py, na2, lane, wid, red,
          d_r, d_i, h_r, h_i, al,
          xC, tC, BC, CC, cC,  xA, tA, BA, CA, cA,  tB);
      period_body<2, 4, PARTIAL>(px, pdt, pB, pC, pxc, py, na2, lane, wid, red,
          d_r, d_i, h_r, h_i, al,
          xB, tB, BB, CB, cB,  xC, tC, BC, CC, cC,  tA);
      px += 6 * 2048; pdt += 6 * 1024; pB += 6 * 160; pC += 6 * 160; pxc += 6 * 160;
      py += 6 * 1024;
    }
    period_body<0, 0, PARTIAL>(px, pdt, pB, pC, pxc, py, na2, lane, wid, red,
        d_r, d_i, h_r, h_i, al,
        xA, tA, BA, CA, cA,  xB, tB, BB, CB, cB,  tC);
    __builtin_amdgcn_s_setprio(0);
  } else {
    // ---------------- g1b branch: 64x64 BK=32 GEMM, z-half, grid-strided ----------------
    constexpr int BK = 32, PAD = 4;
    __shared__ float As[BK][64 + PAD];
    __shared__ float Ws[BK][64 + PAD];
    const int bg = blockIdx.x - 64;   // 0..191
    const int tid = threadIdx.x;
    const int tx = tid & 15;
    const int ty = tid >> 4;
    const int lm = tid & 63;
    const int lk = (tid >> 6) << 3;

    for (int t2 = bg; t2 < 512; t2 += 192) {
      const int m0 = (t2 & 31) << 6;
      const int n0 = (t2 >> 5) << 6;

      float4 a0, a1, w0, w1;
      {
        const float* p = xg + (size_t)(m0 + lm) * 1024 + lk;
        a0 = ((const float4*)p)[0]; a1 = ((const float4*)p)[1];
        const float* pw = Wz + (size_t)(n0 + lm) * 1024 + lk;
        w0 = ((const float4*)pw)[0]; w1 = ((const float4*)pw)[1];
      }
      float acc[4][4] = {{0.f,0.f,0.f,0.f},{0.f,0.f,0.f,0.f},{0.f,0.f,0.f,0.f},{0.f,0.f,0.f,0.f}};
      const int NT = 1024 / BK;
      for (int i = 0; i < NT; ++i) {
        __syncthreads();
        As[lk+0][lm]=a0.x; As[lk+1][lm]=a0.y; As[lk+2][lm]=a0.z; As[lk+3][lm]=a0.w;
        As[lk+4][lm]=a1.x; As[lk+5][lm]=a1.y; As[lk+6][lm]=a1.z; As[lk+7][lm]=a1.w;
        Ws[lk+0][lm]=w0.x; Ws[lk+1][lm]=w0.y; Ws[lk+2][lm]=w0.z; Ws[lk+3][lm]=w0.w;
        Ws[lk+4][lm]=w1.x; Ws[lk+5][lm]=w1.y; Ws[lk+6][lm]=w1.z; Ws[lk+7][lm]=w1.w;
        __syncthreads();
        if (i + 1 < NT) {
          const int k0 = (i + 1) * BK;
          const float* p = xg + (size_t)(m0 + lm) * 1024 + k0 + lk;
          a0 = ((const float4*)p)[0]; a1 = ((const float4*)p)[1];
          const float* pw = Wz + (size_t)(n0 + lm) * 1024 + k0 + lk;
          w0 = ((const float4*)pw)[0]; w1 = ((const float4*)pw)[1];
        }
#pragma unroll
        for (int kk = 0; kk < BK; ++kk) {
          const float4 a = *(const float4*)&As[kk][ty << 2];
          const float4 w = *(const float4*)&Ws[kk][tx << 2];
          const float ar[4] = {a.x, a.y, a.z, a.w};
          const float wr[4] = {w.x, w.y, w.z, w.w};
#pragma unroll
          for (int ii = 0; ii < 4; ++ii)
#pragma unroll
            for (int j = 0; j < 4; ++j)
              acc[ii][j] = fmaf(ar[ii], wr[j], acc[ii][j]);
        }
      }
      const int ncol = n0 + (tx << 2);
#pragma unroll
      for (int i = 0; i < 4; ++i) {
        float vs[4];
#pragma unroll
        for (int j = 0; j < 4; ++j) vs[j] = epi_apply<EPI_SILU>(acc[i][j], 0.f);
        *(float4*)(Cz + (size_t)(m0 + (ty << 2) + i) * 2048 + ncol) = make_float4(vs[0], vs[1], vs[2], vs[3]);
      }
      __syncthreads();   // protect As/Ws before next tile's staging
    }
  }
}

extern "C" void kernel_launch(void* const* d_in, const int* in_sizes, int n_in,
                              void* d_out, int out_size, void* d_ws, size_t ws_size,
                              hipStream_t stream) {
  const float* x     = (const float*)d_in[0];
  const float* W_in  = (const float*)d_in[1];
  const float* W_xp  = (const float*)d_in[2];
  const float* W_dt  = (const float*)d_in[3];
  const float* b_dt  = (const float*)d_in[4];
  const float* W_out = (const float*)d_in[5];
  const float* b_out = (const float*)d_in[6];
  const float* W_res = (const float*)d_in[7];
  const float* A_log = (const float*)d_in[8];
  float* out = (float*)d_out;

  float* ws     = (float*)d_ws;
  float* siluxz = ws;                               // 2048*2048   = 4,194,304 f
  float* xpc    = siluxz + (size_t)2048 * 2048;     // 2048*160    =   327,680 f
  float* dtb    = xpc    + (size_t)2048 * 160;      // 2048*1024   = 2,097,152 f
  float* ybuf   = dtb    + (size_t)2048 * 1024;     // 2048*1024   = 2,097,152 f
  float* ypart  = ybuf   + (size_t)2048 * 1024;     // 16*2048*1024 = 33,554,432 f

  const size_t need_bytes = ((size_t)8716288 + (size_t)33554432) * 4;
  const bool use_part = ws_size >= need_bytes;

  // g1a: x_in half = silu(x @ W_in[0:1024].T)   [64x64 BK=64, grid (32,16)=512]
  gemm_wt<EPI_SILU><<<dim3(32, 16), 256, 0, stream>>>(
      x, 1024, W_in, 1024, nullptr, siluxz, 2048, 1024, 1024);
  // g2+g4 fused: xpc = x_in @ [W_xproj; W_res].T   [32x32, grid (64,5)=320]
  gemm_dualw32<<<dim3(64, 5), 256, 0, stream>>>(
      siluxz, 2048, W_xp, W_res, 1024, xpc, 160, 1024);
  // g3: dt = softplus(xpc[:, :64] @ W_dt.T + b_dt)  K=64 one-shot
  gemm_dt64<<<dim3(32, 16), 256, 0, stream>>>(
      xpc, 160, W_dt, b_dt, dtb, 1024);

  if (use_part) {
    // fused 256 blocks: scan (0..63, private CUs) + grid-strided g1b (64..255)
    scan_g1b<true><<<dim3(256), dim3(256), 0, stream>>>(
        siluxz, xpc, dtb, A_log, ypart, 512,
        x, W_in + (size_t)1024 * 1024, siluxz + 1024);
    // ybuf = (sum_s ypart) * silu(z)  -> g5 is a plain GEMM
    reduce_y_silu<<<dim3(2048), 256, 0, stream>>>(
        (const float4*)ypart, siluxz, (float4*)ybuf, 524288);
  } else {
    zero_kernel<<<dim3(2048), 256, 0, stream>>>((float4*)ybuf, (2048 * 1024) / 4);
    scan_g1b<false><<<dim3(256), dim3(256), 0, stream>>>(
        siluxz, xpc, dtb, A_log, ybuf, 512,
        x, W_in + (size_t)1024 * 1024, siluxz + 1024);
    mul_silu<<<dim3(8192), 256, 0, stream>>>(ybuf, siluxz, 2048 * 1024);
  }

  // g5: out = ybuf @ W_out.T + b_out   [64x64 BK=64, 512 blocks, plain GEMM]
  gemm_wt<EPI_BIAS><<<dim3(32, 16), 256, 0, stream>>>(
      ybuf, 1024, W_out, 1024, b_out, out, 1024, 1024, 1024);
}

// Round 17
// 490.046 us; speedup vs baseline: 1.0174x; 1.0174x over previous
//
#include <hip/hip_runtime.h>
#include <hip/hip_bf16.h>
#include <math.h>

// CircumpunctSSM: B=4, T=512, D=1024, S=16, dt_rank=64. All f32.
// Pipeline (final = R15 config, best measured 490.2 µs):
//   g1a: siluxz[:, 0:1024]  = silu(x @ W_in[0:1024].T)     [64x64 BK=32, 512 blocks]
//   g24: xpc[2048,160]      = x_in @ [W_xproj;W_res].T     [32x32 BK=32, 320 blocks]
//   g3:  dt[2048,1024]      = softplus(xpc[:,:64]@W_dt.T+b_dt) [K=64 one-shot]
//   FUSED scan+g1b (576 blocks):
//     blocks 0..63   : scan (4 waves x 4 elem, 2 steps/barrier, s_setprio(1))
//     blocks 64..575 : g1b = silu(x @ W_in[1024:2048].T) -> siluxz[:, 1024:2048]
//   reduce_y: ybuf = (sum_s ypart[s]) * siluz   [silu fold -> g5 plain GEMM]
//   g5: out = ybuf @ W_out.T + b_out            [64x64 BK=32, 512 blocks]
//
// Session-established rules:
//  - standalone GEMMs need >=2 blocks/CU (R5/R9/R10); BK=32 optimal (R12/R16).
//  - scan: 4 waves x 4 elem optimal (R5 8w null, R7 2-scans bad, R11 1-wave bad);
//    2 steps/barrier is the semantic max (R6); s_barrier beats software gates
//    (R14); lgkm-only drain + reg prefetch keeps globals in flight (R1/R4).
//  - g1b fusion into the scan's CU shadow: -40 µs (R13); 256-block isolation
//    null (R16) — the +16 µs fused overhead is structural.

enum { EPI_NONE=0, EPI_SILU=1, EPI_SPBIAS=2, EPI_BIAS=3 };

template<int EPI>
__device__ __forceinline__ float epi_apply(float v, float b) {
  if constexpr (EPI == EPI_SILU)        { return v / (1.0f + expf(-v)); }
  else if constexpr (EPI == EPI_SPBIAS) { float t = v + b; return fmaxf(t, 0.0f) + log1pf(expf(-fabsf(t))); }
  else if constexpr (EPI == EPI_BIAS)   { return v + b; }
  else return v;
}

// ---------------- 64x64 tile GEMM, BK=32 + register prefetch (g1a, g5) ----------------
template<int EPI, bool HAS_A2>
__global__ __launch_bounds__(256) void gemm_wt(
    const float* __restrict__ A, int lda,
    const float* __restrict__ A2, int lda2,
    const float* __restrict__ W, int ldw,
    const float* __restrict__ bias,
    float* __restrict__ C, int ldc,
    int N, int K)
{
  constexpr int BM = 64, BN = 64, BK = 32, PAD = 4;
  __shared__ float As[BK][BM + PAD];
  __shared__ float Ws[BK][BN + PAD];
  const int m0 = blockIdx.x * BM;
  const int n0 = blockIdx.y * BN;
  const int tid = threadIdx.x;
  const int tx = tid & 15;
  const int ty = tid >> 4;
  const int lm = tid & 63;           // staging row
  const int lk = (tid >> 6) << 3;    // 0,8,16,24 (wave-uniform)

  float4 a0, a1, w0, w1;
  {
    const float* p = A + (size_t)(m0 + lm) * lda + lk;
    a0 = ((const float4*)p)[0]; a1 = ((const float4*)p)[1];
    if (HAS_A2) {
      const float* p2 = A2 + (size_t)(m0 + lm) * lda2 + lk;
      const float4 b0 = ((const float4*)p2)[0], b1 = ((const float4*)p2)[1];
      a0.x*=b0.x; a0.y*=b0.y; a0.z*=b0.z; a0.w*=b0.w;
      a1.x*=b1.x; a1.y*=b1.y; a1.z*=b1.z; a1.w*=b1.w;
    }
    const int n = n0 + lm;
    if (n < N) {
      const float* pw = W + (size_t)n * ldw + lk;
      w0 = ((const float4*)pw)[0]; w1 = ((const float4*)pw)[1];
    } else { w0 = make_float4(0.f,0.f,0.f,0.f); w1 = w0; }
  }

  float acc[4][4] = {{0.f,0.f,0.f,0.f},{0.f,0.f,0.f,0.f},{0.f,0.f,0.f,0.f},{0.f,0.f,0.f,0.f}};
  const int NT = K / BK;

  for (int i = 0; i < NT; ++i) {
    __syncthreads();   // protect previous iteration's LDS reads
    As[lk+0][lm]=a0.x; As[lk+1][lm]=a0.y; As[lk+2][lm]=a0.z; As[lk+3][lm]=a0.w;
    As[lk+4][lm]=a1.x; As[lk+5][lm]=a1.y; As[lk+6][lm]=a1.z; As[lk+7][lm]=a1.w;
    Ws[lk+0][lm]=w0.x; Ws[lk+1][lm]=w0.y; Ws[lk+2][lm]=w0.z; Ws[lk+3][lm]=w0.w;
    Ws[lk+4][lm]=w1.x; Ws[lk+5][lm]=w1.y; Ws[lk+6][lm]=w1.z; Ws[lk+7][lm]=w1.w;
    __syncthreads();
    if (i + 1 < NT) {
      const int k0 = (i + 1) * BK;
      const float* p = A + (size_t)(m0 + lm) * lda + k0 + lk;
      a0 = ((const float4*)p)[0]; a1 = ((const float4*)p)[1];
      if (HAS_A2) {
        const float* p2 = A2 + (size_t)(m0 + lm) * lda2 + k0 + lk;
        const float4 b0 = ((const float4*)p2)[0], b1 = ((const float4*)p2)[1];
        a0.x*=b0.x; a0.y*=b0.y; a0.z*=b0.z; a0.w*=b0.w;
        a1.x*=b1.x; a1.y*=b1.y; a1.z*=b1.z; a1.w*=b1.w;
      }
      const int n = n0 + lm;
      if (n < N) {
        const float* pw = W + (size_t)n * ldw + k0 + lk;
        w0 = ((const float4*)pw)[0]; w1 = ((const float4*)pw)[1];
      } else { w0 = make_float4(0.f,0.f,0.f,0.f); w1 = w0; }
    }
#pragma unroll
    for (int kk = 0; kk < BK; ++kk) {
      const float4 a = *(const float4*)&As[kk][ty << 2];
      const float4 w = *(const float4*)&Ws[kk][tx << 2];
      const float ar[4] = {a.x, a.y, a.z, a.w};
      const float wr[4] = {w.x, w.y, w.z, w.w};
#pragma unroll
      for (int ii = 0; ii < 4; ++ii)
#pragma unroll
        for (int j = 0; j < 4; ++j)
          acc[ii][j] = fmaf(ar[ii], wr[j], acc[ii][j]);
    }
  }

  const int ncol = n0 + (tx << 2);
  float bj[4] = {0.f, 0.f, 0.f, 0.f};
  if constexpr (EPI == EPI_SPBIAS || EPI == EPI_BIAS) {
    if (ncol < N) { const float4 bv = *(const float4*)(bias + ncol); bj[0]=bv.x; bj[1]=bv.y; bj[2]=bv.z; bj[3]=bv.w; }
  }
  if (ncol < N) {
#pragma unroll
    for (int i = 0; i < 4; ++i) {
      float vs[4];
#pragma unroll
      for (int j = 0; j < 4; ++j) vs[j] = epi_apply<EPI>(acc[i][j], bj[j]);
      *(float4*)(C + (size_t)(m0 + (ty << 2) + i) * ldc + ncol) = make_float4(vs[0], vs[1], vs[2], vs[3]);
    }
  }
}

// ---------------- 32x32 dual-W GEMM (fused g2+g4), BK=32 + prefetch ----------------
__global__ __launch_bounds__(256) void gemm_dualw32(
    const float* __restrict__ A, int lda,
    const float* __restrict__ W1,
    const float* __restrict__ W2, int ldw,
    float* __restrict__ C, int ldc, int K)
{
  constexpr int BM = 32, BN = 32, BK = 32, PAD = 4;
  __shared__ float As[BK][BM + PAD];
  __shared__ float Ws[BK][BN + PAD];
  const int m0 = blockIdx.x * BM;
  const int n0 = blockIdx.y * BN;
  const int tid = threadIdx.x;
  const int tx = tid & 15;          // n-pos (2 cols each)
  const int ty = tid >> 4;          // m-pos (2 rows each)
  const int lm = tid & 31;          // staging row
  const int lk = (tid >> 5) << 2;   // 0,4,...,28

  const int n = n0 + lm;
  const float* wrow = (n < 128) ? (W1 + (size_t)n * ldw) : (W2 + (size_t)(n - 128) * ldw);

  float4 av = *(const float4*)(A + (size_t)(m0 + lm) * lda + lk);
  float4 wv = *(const float4*)(wrow + lk);

  float acc[2][2] = {{0.f,0.f},{0.f,0.f}};
  const int NT = K / BK;
  for (int i = 0; i < NT; ++i) {
    __syncthreads();
    As[lk+0][lm]=av.x; As[lk+1][lm]=av.y; As[lk+2][lm]=av.z; As[lk+3][lm]=av.w;
    Ws[lk+0][lm]=wv.x; Ws[lk+1][lm]=wv.y; Ws[lk+2][lm]=wv.z; Ws[lk+3][lm]=wv.w;
    __syncthreads();
    if (i + 1 < NT) {
      const int k0 = (i + 1) * BK;
      av = *(const float4*)(A + (size_t)(m0 + lm) * lda + k0 + lk);
      wv = *(const float4*)(wrow + k0 + lk);
    }
#pragma unroll
    for (int kk = 0; kk < BK; ++kk) {
      const float2 a = *(const float2*)&As[kk][ty << 1];
      const float2 w = *(const float2*)&Ws[kk][tx << 1];
      acc[0][0] = fmaf(a.x, w.x, acc[0][0]);
      acc[0][1] = fmaf(a.x, w.y, acc[0][1]);
      acc[1][0] = fmaf(a.y, w.x, acc[1][0]);
      acc[1][1] = fmaf(a.y, w.y, acc[1][1]);
    }
  }
  const int ncol = n0 + (tx << 1);
  float* pc = C + (size_t)(m0 + (ty << 1)) * ldc + ncol;
  *(float2*)pc         = make_float2(acc[0][0], acc[0][1]);
  *(float2*)(pc + ldc) = make_float2(acc[1][0], acc[1][1]);
}

// ---------------- g3: dt = softplus(xpc[:,:64] @ W_dt.T + b_dt), K=64 one-shot ----
__global__ __launch_bounds__(256) void gemm_dt64(
    const float* __restrict__ A, int lda,
    const float* __restrict__ W,
    const float* __restrict__ bias,
    float* __restrict__ C, int ldc)
{
  __shared__ float As[64][68];
  __shared__ float Ws[64][68];
  const int m0 = blockIdx.x * 64;
  const int n0 = blockIdx.y * 64;
  const int tid = threadIdx.x;
  const int lm = tid & 63;
  const int kq = (tid >> 6) << 4;

  {
    const float* pa = A + (size_t)(m0 + lm) * lda + kq;
    const float4 a0 = ((const float4*)pa)[0];
    const float4 a1 = ((const float4*)pa)[1];
    const float4 a2 = ((const float4*)pa)[2];
    const float4 a3 = ((const float4*)pa)[3];
    const float* pw = W + (size_t)(n0 + lm) * 64 + kq;
    const float4 w0 = ((const float4*)pw)[0];
    const float4 w1 = ((const float4*)pw)[1];
    const float4 w2 = ((const float4*)pw)[2];
    const float4 w3 = ((const float4*)pw)[3];
    As[kq+ 0][lm]=a0.x; As[kq+ 1][lm]=a0.y; As[kq+ 2][lm]=a0.z; As[kq+ 3][lm]=a0.w;
    As[kq+ 4][lm]=a1.x; As[kq+ 5][lm]=a1.y; As[kq+ 6][lm]=a1.z; As[kq+ 7][lm]=a1.w;
    As[kq+ 8][lm]=a2.x; As[kq+ 9][lm]=a2.y; As[kq+10][lm]=a2.z; As[kq+11][lm]=a2.w;
    As[kq+12][lm]=a3.x; As[kq+13][lm]=a3.y; As[kq+14][lm]=a3.z; As[kq+15][lm]=a3.w;
    Ws[kq+ 0][lm]=w0.x; Ws[kq+ 1][lm]=w0.y; Ws[kq+ 2][lm]=w0.z; Ws[kq+ 3][lm]=w0.w;
    Ws[kq+ 4][lm]=w1.x; Ws[kq+ 5][lm]=w1.y; Ws[kq+ 6][lm]=w1.z; Ws[kq+ 7][lm]=w1.w;
    Ws[kq+ 8][lm]=w2.x; Ws[kq+ 9][lm]=w2.y; Ws[kq+10][lm]=w2.z; Ws[kq+11][lm]=w2.w;
    Ws[kq+12][lm]=w3.x; Ws[kq+13][lm]=w3.y; Ws[kq+14][lm]=w3.z; Ws[kq+15][lm]=w3.w;
  }
  __syncthreads();

  const int tx = tid & 15;
  const int ty = tid >> 4;
  float acc[4][4] = {{0.f,0.f,0.f,0.f},{0.f,0.f,0.f,0.f},{0.f,0.f,0.f,0.f},{0.f,0.f,0.f,0.f}};
#pragma unroll 16
  for (int kk = 0; kk < 64; ++kk) {
    const float4 a = *(const float4*)&As[kk][ty << 2];
    const float4 w = *(const float4*)&Ws[kk][tx << 2];
    const float ar[4] = {a.x, a.y, a.z, a.w};
    const float wr[4] = {w.x, w.y, w.z, w.w};
#pragma unroll
    for (int i = 0; i < 4; ++i)
#pragma unroll
      for (int j = 0; j < 4; ++j)
        acc[i][j] = fmaf(ar[i], wr[j], acc[i][j]);
  }

  const int ncol = n0 + (tx << 2);
  const float4 bv = *(const float4*)(bias + ncol);
  const float bj[4] = {bv.x, bv.y, bv.z, bv.w};
#pragma unroll
  for (int i = 0; i < 4; ++i) {
    float vs[4];
#pragma unroll
    for (int j = 0; j < 4; ++j) vs[j] = epi_apply<EPI_SPBIAS>(acc[i][j], bj[j]);
    *(float4*)(C + (size_t)(m0 + (ty << 2) + i) * ldc + ncol) = make_float4(vs[0], vs[1], vs[2], vs[3]);
  }
}

__global__ void zero_kernel(float4* __restrict__ p, int n4) {
  const int i = blockIdx.x * blockDim.x + threadIdx.x;
  if (i < n4) p[i] = make_float4(0.f, 0.f, 0.f, 0.f);
}

// ybuf[i] = (sum_s ypart[s][i]) * siluz[i]
__global__ __launch_bounds__(256) void reduce_y_silu(
    const float4* __restrict__ yp, const float* __restrict__ siluxz,
    float4* __restrict__ yo, int n4)
{
  const int i = blockIdx.x * blockDim.x + threadIdx.x;
  if (i >= n4) return;
  float4 a = yp[i];
#pragma unroll
  for (int s = 1; s < 16; ++s) {
    const float4 v = yp[(size_t)s * 524288 + i];
    a.x += v.x; a.y += v.y; a.z += v.z; a.w += v.w;
  }
  const int row = i >> 8;          // 256 float4 per row of [2048][1024]
  const int c4  = i & 255;
  const float4 z = *(const float4*)(siluxz + (size_t)row * 2048 + 1024 + (c4 << 2));
  a.x *= z.x; a.y *= z.y; a.z *= z.z; a.w *= z.w;
  yo[i] = a;
}

// legacy (atomic fallback path)
__global__ __launch_bounds__(256) void mul_silu(
    float* __restrict__ y, const float* __restrict__ siluxz, int n)
{
  const int i = blockIdx.x * blockDim.x + threadIdx.x;
  if (i >= n) return;
  const int row = i >> 10;
  const int col = i & 1023;
  y[i] *= siluxz[(size_t)row * 2048 + 1024 + col];
}

// --- DPP wave64 sum: 6 dependent full-rate VALU adds. Lane 63 = full sum.
template<int CTRL>
__device__ __forceinline__ float dpp_fadd(float x) {
  const int s = __builtin_amdgcn_update_dpp(0, __float_as_int(x), CTRL, 0xF, 0xF, true);
  return x + __int_as_float(s);
}
__device__ __forceinline__ float wave64_sum_l63(float x) {
  x = dpp_fadd<0x111>(x);   // row_shr:1
  x = dpp_fadd<0x112>(x);   // row_shr:2
  x = dpp_fadd<0x114>(x);   // row_shr:4
  x = dpp_fadd<0x118>(x);   // row_shr:8
  x = dpp_fadd<0x142>(x);   // row_bcast:15
  x = dpp_fadd<0x143>(x);   // row_bcast:31
  return x;
}

// comp for one row; outputs alpha. R9 fold: cm*rr*invr = rr * m2^(-1/6);
// alpha via exp2 with hoisted na2 = -a_s*log2e.
__device__ __forceinline__ void comp_block(const float4& dtv, const float na2,
    const float (&h_r)[4], const float (&h_i)[4], float (&al_out)[4],
    float& wr, float& wi)
{
  const float ta[4] = {dtv.x, dtv.y, dtv.z, dtv.w};
  float sr = 0.f, si = 0.f;
#pragma unroll
  for (int e = 0; e < 4; ++e) {
    const float a = exp2f(ta[e] * na2);
    al_out[e] = a;
    const float om    = 1.0f - a;
    const float rel_r = h_r[e] * om, rel_i = h_i[e] * om;
    const float m2 = fmaf(rel_r, rel_r, fmaf(rel_i, rel_i, 1e-8f));
    const float u  = exp2f(log2f(m2) * (-1.0f / 6.0f));   // mag^(2/3)/mag
    const float rr = rel_r + 1e-10f;
    float cr = rr * u;    cr = fminf(fmaxf(cr, -10.f), 10.f);
    float ci = rel_i * u; ci = fminf(fmaxf(ci, -10.f), 10.f);
    sr += cr; si += ci;
  }
  wr = wave64_sum_l63(sr);
  wi = wave64_sum_l63(si);
}

// One time-step. R9 fold: sfac = Tg * md2^(-1/4).
template<bool PARTIAL>
__device__ __forceinline__ void step_update(
    float& d_r, float& d_i, const float avg_r, const float avg_i,
    const float2& cx, const float4& xv, const float4& dtv,
    const float2& Bv, const float2& Cv,
    const float (&alv)[4], float (&h_r)[4], float (&h_i)[4],
    float* py)
{
  d_r = fmaf(0.01f, avg_r, d_r);
  d_i = fmaf(0.01f, avg_i, d_i);
  const float dm2c = fmaf(d_r, d_r, fmaf(d_i, d_i, 1e-8f));
  if (dm2c > 400.f) { const float sc = 20.f * __builtin_amdgcn_rsqf(dm2c); d_r *= sc; d_i *= sc; }

  const float xr2 = cx.x + 1e-10f;
  const float irx = __builtin_amdgcn_rsqf(fmaf(xr2, xr2, fmaf(cx.y, cx.y, 1e-38f)));
  const float dr2 = d_r + 1e-10f;
  const float ird = __builtin_amdgcn_rsqf(fmaf(dr2, dr2, fmaf(d_i, d_i, 1e-38f)));
  const float cosdp = fmaf(xr2, dr2, cx.y * d_i) * irx * ird;
  const float Tg  = 0.5f * (1.0f + cosdp);
  const float md2 = fmaf(d_r, d_r, fmaf(d_i, d_i, 1e-8f));
  const float sf  = Tg * exp2f(log2f(md2) * -0.25f);
  const float s_r = d_r * sf, s_i = d_i * sf;

  const float xa[4] = {xv.x, xv.y, xv.z, xv.w};
  const float ta[4] = {dtv.x, dtv.y, dtv.z, dtv.w};
  float yv[4];
#pragma unroll
  for (int e = 0; e < 4; ++e) {
    const float bx_r = fmaf(Bv.x, xa[e], s_r) * ta[e];
    const float bx_i = fmaf(Bv.y, xa[e], s_i) * ta[e];
    h_r[e] = fmaf(h_r[e], alv[e], bx_r);
    h_i[e] = fmaf(h_i[e], alv[e], bx_i);
    yv[e] = fmaf(Cv.x, h_r[e], -(Cv.y * h_i[e]));
  }
  if (PARTIAL) {
    *(float4*)py = make_float4(yv[0], yv[1], yv[2], yv[3]);
  } else {
#pragma unroll
    for (int e = 0; e < 4; ++e) atomicAdd(py + e, yv[e]);
  }
}

// One barrier PERIOD = two time-steps (rows RO, RO+1) + comp for row RO+2.
// xpc-derived streams (B/C/xc) have row stride 160.
template<int RB, int RO, bool PARTIAL>
__device__ __forceinline__ void period_body(
    const float* __restrict__ px, const float* __restrict__ pdt,
    const float* __restrict__ pB, const float* __restrict__ pC,
    const float* __restrict__ pxc, float* __restrict__ py,
    const float na2, const int lane, const int wid,
    float (*red)[4][4],
    float& d_r, float& d_i,
    float (&h_r)[4], float (&h_i)[4], float (&al)[4],
    float4& x0, float4& t0, float2& B0, float2& C0, float2& c0,
    float4& x1, float4& t1, float2& B1, float2& C1, float2& c1,
    const float4& t2)
{
  // phase 1: read previous period's partials
  const float4 qa = *(const float4*)&red[RB][0][0];
  const float4 qb = *(const float4*)&red[RB][1][0];
  const float4 qc = *(const float4*)&red[RB][2][0];
  const float4 qd = *(const float4*)&red[RB][3][0];

  // even step (row RO)
  step_update<PARTIAL>(d_r, d_i,
      (qa.x + qb.x + qc.x + qd.x) * (1.0f / 1024.0f),
      (qa.y + qb.y + qc.y + qd.y) * (1.0f / 1024.0f),
      c0, x0, t0, B0, C0, al, h_r, h_i, py + (size_t)RO * 1024);

  // refill slot0 <- row RO+3 (in flight across the barrier; tail reads land
  // in-workspace and are unused)
  x0 = *(const float4*)(px  + (size_t)(RO + 3) * 2048);
  t0 = *(const float4*)(pdt + (size_t)(RO + 3) * 1024);
  B0 = *(const float2*)(pB  + (RO + 3) * 160);
  C0 = *(const float2*)(pC  + (RO + 3) * 160);
  c0 = *(const float2*)(pxc + (RO + 3) * 160);

  // comp for odd row (RO+1) from h(RO)
  float al1[4], w1r, w1i;
  comp_block(t1, na2, h_r, h_i, al1, w1r, w1i);

  // odd step (row RO+1)
  step_update<PARTIAL>(d_r, d_i,
      (qa.z + qb.z + qc.z + qd.z) * (1.0f / 1024.0f),
      (qa.w + qb.w + qc.w + qd.w) * (1.0f / 1024.0f),
      c1, x1, t1, B1, C1, al1, h_r, h_i, py + (size_t)(RO + 1) * 1024);

  // refill slot1 <- row RO+4
  x1 = *(const float4*)(px  + (size_t)(RO + 4) * 2048);
  t1 = *(const float4*)(pdt + (size_t)(RO + 4) * 1024);
  B1 = *(const float2*)(pB  + (RO + 4) * 160);
  C1 = *(const float2*)(pC  + (RO + 4) * 160);
  c1 = *(const float2*)(pxc + (RO + 4) * 160);

  // comp for next even row (RO+2) from h(RO+1); alpha carried out in al
  float w2r, w2i;
  comp_block(t2, na2, h_r, h_i, al, w2r, w2i);

  // one ds_write_b128 carries BOTH partials
  if (lane == 63) *(float4*)&red[(RB + 1) % 3][wid][0] = make_float4(w1r, w1i, w2r, w2i);

  // raw barrier — LDS-only drain; global loads/stores stay in flight
  asm volatile("s_waitcnt lgkmcnt(0)" ::: "memory");
  __builtin_amdgcn_s_barrier();
  asm volatile("" ::: "memory");
}

// FUSED kernel: blocks 0..63 = scan (one (b,s) each, 4 waves, setprio(1));
// blocks 64..575 = g1b GEMM tiles (z-half of g1). Independent work: g1b's
// output (siluxz cols 1024+) is consumed only by reduce_y_silu/g5, after this.
template<bool PARTIAL>
__global__ __launch_bounds__(256) void scan_g1b(
    const float* __restrict__ xin,   // siluxz base, ld 2048 (cols 0..1023 = x_in)
    const float* __restrict__ xpc,   // ld 160
    const float* __restrict__ dtb,   // ld 1024
    const float* __restrict__ A_log, // [16]
    float* __restrict__ ybase,       // PARTIAL ? ypart : ybuf (pre-zeroed)
    int T,
    const float* __restrict__ xg,    // x input, ld 1024 (g1b A operand)
    const float* __restrict__ Wz,    // W_in + 1024*1024 (z-half rows)
    float* __restrict__ Cz)          // siluxz + 1024, ld 2048
{
  if (blockIdx.x < 64) {
    // ---------------- scan branch ----------------
    __builtin_amdgcn_s_setprio(1);   // favor scan waves in CU issue arbitration

    const int b = blockIdx.x >> 4;
    const int s = blockIdx.x & 15;
    const int d0 = threadIdx.x << 2;
    const int lane = threadIdx.x & 63;
    const int wid = threadIdx.x >> 6;   // 0..3

    __shared__ __align__(16) float red[3][4][4];

    const float a_s = expf(A_log[s]);
    const float na2 = -a_s * 1.4426950408889634f;
    const float phase = (float)(6.283185307179586 * (double)s / 16.0);
    float d_r = 0.01f * cosf(phase);
    float d_i = 0.01f * sinf(phase);
    float h_r[4] = {0.f,0.f,0.f,0.f};
    float h_i[4] = {0.f,0.f,0.f,0.f};
    float al[4];

    const size_t rb = (size_t)b * T;
    const float* px  = xin + rb * 2048 + d0;
    const float* pdt = dtb + rb * 1024 + d0;
    const float* pB  = xpc + rb * 160 + 64 + 2 * s;
    const float* pC  = xpc + rb * 160 + 96 + 2 * s;
    const float* pxc = xpc + rb * 160 + 128 + 2 * s;
    float* py = PARTIAL ? (ybase + (size_t)s * (4 * 512 * 1024) + rb * 1024 + d0)
                        : (ybase + rb * 1024 + d0);

    float4 xA = *(const float4*)px;
    float4 tA = *(const float4*)pdt;
    float2 BA = *(const float2*)pB;
    float2 CA = *(const float2*)pC;
    float2 cA = *(const float2*)pxc;
    float4 xB = *(const float4*)(px + 2048);
    float4 tB = *(const float4*)(pdt + 1024);
    float2 BB = *(const float2*)(pB + 160);
    float2 CB = *(const float2*)(pC + 160);
    float2 cB = *(const float2*)(pxc + 160);
    float4 xC = *(const float4*)(px + 2 * 2048);
    float4 tC = *(const float4*)(pdt + 2 * 1024);
    float2 BC = *(const float2*)(pB + 2 * 160);
    float2 CC = *(const float2*)(pC + 2 * 160);
    float2 cC = *(const float2*)(pxc + 2 * 160);

    {
      float w0r, w0i;
      comp_block(tA, na2, h_r, h_i, al, w0r, w0i);
      if (lane == 63) *(float4*)&red[0][wid][0] = make_float4(0.f, 0.f, w0r, w0i);
    }
    __syncthreads();

    for (int it = 0; it < 85; ++it) {
      period_body<0, 0, PARTIAL>(px, pdt, pB, pC, pxc, py, na2, lane, wid, red,
          d_r, d_i, h_r, h_i, al,
          xA, tA, BA, CA, cA,  xB, tB, BB, CB, cB,  tC);
      period_body<1, 2, PARTIAL>(px, pdt, pB, pC, pxc, py, na2, lane, wid, red,
          d_r, d_i, h_r, h_i, al,
          xC, tC, BC, CC, cC,  xA, tA, BA, CA, cA,  tB);
      period_body<2, 4, PARTIAL>(px, pdt, pB, pC, pxc, py, na2, lane, wid, red,
          d_r, d_i, h_r, h_i, al,
          xB, tB, BB, CB, cB,  xC, tC, BC, CC, cC,  tA);
      px += 6 * 2048; pdt += 6 * 1024; pB += 6 * 160; pC += 6 * 160; pxc += 6 * 160;
      py += 6 * 1024;
    }
    period_body<0, 0, PARTIAL>(px, pdt, pB, pC, pxc, py, na2, lane, wid, red,
        d_r, d_i, h_r, h_i, al,
        xA, tA, BA, CA, cA,  xB, tB, BB, CB, cB,  tC);
    __builtin_amdgcn_s_setprio(0);
  } else {
    // ---------------- g1b branch: 64x64 BK=32 GEMM, z-half ----------------
    // b2 in 0..511: m0 = (b2&31)*64 (M=2048), n0 = (b2>>5)*64 (N=1024, exact).
    constexpr int BK = 32, PAD = 4;
    __shared__ float As[BK][64 + PAD];
    __shared__ float Ws[BK][64 + PAD];
    const int b2 = blockIdx.x - 64;
    const int m0 = (b2 & 31) << 6;
    const int n0 = (b2 >> 5) << 6;
    const int tid = threadIdx.x;
    const int tx = tid & 15;
    const int ty = tid >> 4;
    const int lm = tid & 63;
    const int lk = (tid >> 6) << 3;

    float4 a0, a1, w0, w1;
    {
      const float* p = xg + (size_t)(m0 + lm) * 1024 + lk;
      a0 = ((const float4*)p)[0]; a1 = ((const float4*)p)[1];
      const float* pw = Wz + (size_t)(n0 + lm) * 1024 + lk;
      w0 = ((const float4*)pw)[0]; w1 = ((const float4*)pw)[1];
    }
    float acc[4][4] = {{0.f,0.f,0.f,0.f},{0.f,0.f,0.f,0.f},{0.f,0.f,0.f,0.f},{0.f,0.f,0.f,0.f}};
    const int NT = 1024 / BK;
    for (int i = 0; i < NT; ++i) {
      __syncthreads();
      As[lk+0][lm]=a0.x; As[lk+1][lm]=a0.y; As[lk+2][lm]=a0.z; As[lk+3][lm]=a0.w;
      As[lk+4][lm]=a1.x; As[lk+5][lm]=a1.y; As[lk+6][lm]=a1.z; As[lk+7][lm]=a1.w;
      Ws[lk+0][lm]=w0.x; Ws[lk+1][lm]=w0.y; Ws[lk+2][lm]=w0.z; Ws[lk+3][lm]=w0.w;
      Ws[lk+4][lm]=w1.x; Ws[lk+5][lm]=w1.y; Ws[lk+6][lm]=w1.z; Ws[lk+7][lm]=w1.w;
      __syncthreads();
      if (i + 1 < NT) {
        const int k0 = (i + 1) * BK;
        const float* p = xg + (size_t)(m0 + lm) * 1024 + k0 + lk;
        a0 = ((const float4*)p)[0]; a1 = ((const float4*)p)[1];
        const float* pw = Wz + (size_t)(n0 + lm) * 1024 + k0 + lk;
        w0 = ((const float4*)pw)[0]; w1 = ((const float4*)pw)[1];
      }
#pragma unroll
      for (int kk = 0; kk < BK; ++kk) {
        const float4 a = *(const float4*)&As[kk][ty << 2];
        const float4 w = *(const float4*)&Ws[kk][tx << 2];
        const float ar[4] = {a.x, a.y, a.z, a.w};
        const float wr[4] = {w.x, w.y, w.z, w.w};
#pragma unroll
        for (int ii = 0; ii < 4; ++ii)
#pragma unroll
          for (int j = 0; j < 4; ++j)
            acc[ii][j] = fmaf(ar[ii], wr[j], acc[ii][j]);
      }
    }
    const int ncol = n0 + (tx << 2);
#pragma unroll
    for (int i = 0; i < 4; ++i) {
      float vs[4];
#pragma unroll
      for (int j = 0; j < 4; ++j) vs[j] = epi_apply<EPI_SILU>(acc[i][j], 0.f);
      *(float4*)(Cz + (size_t)(m0 + (ty << 2) + i) * 2048 + ncol) = make_float4(vs[0], vs[1], vs[2], vs[3]);
    }
  }
}

extern "C" void kernel_launch(void* const* d_in, const int* in_sizes, int n_in,
                              void* d_out, int out_size, void* d_ws, size_t ws_size,
                              hipStream_t stream) {
  const float* x     = (const float*)d_in[0];
  const float* W_in  = (const float*)d_in[1];
  const float* W_xp  = (const float*)d_in[2];
  const float* W_dt  = (const float*)d_in[3];
  const float* b_dt  = (const float*)d_in[4];
  const float* W_out = (const float*)d_in[5];
  const float* b_out = (const float*)d_in[6];
  const float* W_res = (const float*)d_in[7];
  const float* A_log = (const float*)d_in[8];
  float* out = (float*)d_out;

  float* ws     = (float*)d_ws;
  float* siluxz = ws;                               // 2048*2048   = 4,194,304 f
  float* xpc    = siluxz + (size_t)2048 * 2048;     // 2048*160    =   327,680 f
  float* dtb    = xpc    + (size_t)2048 * 160;      // 2048*1024   = 2,097,152 f
  float* ybuf   = dtb    + (size_t)2048 * 1024;     // 2048*1024   = 2,097,152 f
  float* ypart  = ybuf   + (size_t)2048 * 1024;     // 16*2048*1024 = 33,554,432 f

  const size_t need_bytes = ((size_t)8716288 + (size_t)33554432) * 4;
  const bool use_part = ws_size >= need_bytes;

  // g1a: x_in half = silu(x @ W_in[0:1024].T)   [64x64 BK=32, grid (32,16)=512]
  gemm_wt<EPI_SILU, false><<<dim3(32, 16), 256, 0, stream>>>(
      x, 1024, nullptr, 0, W_in, 1024, nullptr, siluxz, 2048, 1024, 1024);
  // g2+g4 fused: xpc = x_in @ [W_xproj; W_res].T   [32x32, grid (64,5)=320]
  gemm_dualw32<<<dim3(64, 5), 256, 0, stream>>>(
      siluxz, 2048, W_xp, W_res, 1024, xpc, 160, 1024);
  // g3: dt = softplus(xpc[:, :64] @ W_dt.T + b_dt)  K=64 one-shot
  gemm_dt64<<<dim3(32, 16), 256, 0, stream>>>(
      xpc, 160, W_dt, b_dt, dtb, 1024);

  if (use_part) {
    // fused: scan (blocks 0..63) + g1b z-half GEMM (blocks 64..575)
    scan_g1b<true><<<dim3(64 + 512), dim3(256), 0, stream>>>(
        siluxz, xpc, dtb, A_log, ypart, 512,
        x, W_in + (size_t)1024 * 1024, siluxz + 1024);
    // ybuf = (sum_s ypart) * silu(z)  -> g5 is a plain GEMM
    reduce_y_silu<<<dim3(2048), 256, 0, stream>>>(
        (const float4*)ypart, siluxz, (float4*)ybuf, 524288);
  } else {
    zero_kernel<<<dim3(2048), 256, 0, stream>>>((float4*)ybuf, (2048 * 1024) / 4);
    scan_g1b<false><<<dim3(64 + 512), dim3(256), 0, stream>>>(
        siluxz, xpc, dtb, A_log, ybuf, 512,
        x, W_in + (size_t)1024 * 1024, siluxz + 1024);
    mul_silu<<<dim3(8192), 256, 0, stream>>>(ybuf, siluxz, 2048 * 1024);
  }

  // g5: out = ybuf @ W_out.T + b_out   [64x64 BK=32, 512 blocks, plain GEMM]
  gemm_wt<EPI_BIAS, false><<<dim3(32, 16), 256, 0, stream>>>(
      ybuf, 1024, nullptr, 0, W_out, 1024, b_out, out, 1024, 1024, 1024);
}